// Round 1
// baseline (787.786 us; speedup 1.0000x reference)
//
#include <hip/hip_runtime.h>
#include <hip/hip_bf16.h>
#include <math.h>

#define NL 30
#define NM 80
#define Bx 8
#define Tx 8192

typedef short short8 __attribute__((ext_vector_type(8)));
typedef float f32x4 __attribute__((ext_vector_type(4)));
typedef unsigned int u32x2 __attribute__((ext_vector_type(2)));
typedef unsigned int u32x4 __attribute__((ext_vector_type(4)));

__device__ __forceinline__ float bf2f(unsigned short u) {
    union { unsigned int u; float f; } v; v.u = ((unsigned int)u) << 16; return v.f;
}
__device__ __forceinline__ unsigned short f2bf(float f) {
    union { float f; unsigned int u; } v; v.f = f;
    unsigned int r = v.u + 0x7FFFu + ((v.u >> 16) & 1u);
    return (unsigned short)(r >> 16);
}

// ---------------- time-embedding MLP (tiny, 1 block) ----------------
__global__ void te_kernel(const int* __restrict__ tin,
                          const float* __restrict__ w1, const float* __restrict__ b1,
                          const float* __restrict__ w2, const float* __restrict__ b2,
                          float* __restrict__ te_out) {
    __shared__ float emb[128];
    __shared__ float h1[512];
    int tid = threadIdx.x;
    for (int b = 0; b < Bx; ++b) {
        if (tid < 64) {
            float fr = expf(-(float)tid * (logf(10000.f) / 63.f));
            float ang = (float)tin[b] * fr;
            emb[tid] = sinf(ang);
            emb[tid + 64] = cosf(ang);
        }
        __syncthreads();
        {
            float a = b1[tid];
            const float* wr = w1 + tid * 128;
            for (int k = 0; k < 128; ++k) a = fmaf(emb[k], wr[k], a);
            float sp = (a > 15.f) ? a : log1pf(expf(a));
            h1[tid] = a * tanhf(sp);
        }
        __syncthreads();
        if (tid < 128) {
            float o = b2[tid];
            const float* wr2 = w2 + tid * 512;
            for (int k = 0; k < 512; ++k) o = fmaf(h1[k], wr2[k], o);
            te_out[b * 128 + tid] = o;
        }
        __syncthreads();
    }
}

// ---------------- per-layer (b,ch) bias: dconv_b + sign(tp) + sign(cp) ----------------
__global__ void gbias_kernel(const float* __restrict__ te,
                             const float* __restrict__ cemb,
                             const float* __restrict__ tpw, const float* __restrict__ tpb,
                             const float* __restrict__ cpw, const float* __restrict__ cpb,
                             const float* __restrict__ dcb,
                             float* __restrict__ gbias) {
    int l = blockIdx.x >> 3;
    int b = blockIdx.x & 7;
    int ch = threadIdx.x;
    float tp = tpb[l * 128 + ch];
    const float* wr = tpw + (size_t)(l * 128 + ch) * 128;
    const float* tb = te + b * 128;
    for (int k = 0; k < 128; ++k) tp = fmaf(tb[k], wr[k], tp);
    float s1 = tp / fmaxf(fabsf(tp), 1e-12f);
    float cp = cpb[l * 128 + ch];
    const float* wcp = cpw + (size_t)(l * 128 + ch) * 256;
    const float* cb = cemb + b * 256;
    for (int k = 0; k < 256; ++k) cp = fmaf(cb[k], wcp[k], cp);
    float s2 = cp / fmaxf(fabsf(cp), 1e-12f);
    gbias[(l * 8 + b) * 128 + ch] = dcb[l * 128 + ch] + s1 + s2;
}

// ---------------- weight prep: f32 -> bf16, conv re-laid [l][tap][oc][ic] ----------------
__global__ void prep_kernel(const float* __restrict__ dconv_w, const float* __restrict__ rs_w,
                            unsigned short* __restrict__ wc, unsigned short* __restrict__ wr) {
    int idx = blockIdx.x * 256 + threadIdx.x;
    const int tot1 = NL * 3 * 128 * 64;  // 737280
    if (idx < tot1) {
        int l = idx / 24576;
        int r = idx - l * 24576;
        int k = r >> 13;
        int r2 = r & 8191;
        int oc = r2 >> 6;
        int ic = r2 & 63;
        wc[idx] = f2bf(dconv_w[((size_t)(l * 128 + oc) * 64 + ic) * 3 + k]);
    } else {
        int j = idx - tot1;
        if (j < NL * 128 * 64) wr[j] = f2bf(rs_w[j]);
    }
}

// ---------------- input conv 80->64 + transpose to (B,T,64) bf16 ----------------
__global__ void in_conv_kernel(const float* __restrict__ x, const float* __restrict__ w,
                               const float* __restrict__ bias, unsigned short* __restrict__ h0) {
    __shared__ float wT[NM][64];
    int tid = threadIdx.x;
    for (int i = tid; i < NM * 64; i += 256) {
        int m = i >> 6, c = i & 63;
        wT[m][c] = w[c * NM + m];
    }
    __syncthreads();
    int b = blockIdx.y;
    int t = blockIdx.x * 128 + (tid >> 1);
    int ch0 = (tid & 1) * 32;
    const float* xp = x + (size_t)b * NM * Tx + t;
    float acc[32];
    #pragma unroll
    for (int c = 0; c < 32; ++c) acc[c] = bias[ch0 + c];
    for (int m = 0; m < NM; ++m) {
        float xv = xp[(size_t)m * Tx];
        #pragma unroll
        for (int c = 0; c < 32; ++c) acc[c] = fmaf(xv, wT[m][ch0 + c], acc[c]);
    }
    unsigned short* hp = h0 + ((size_t)b * Tx + t) * 64 + ch0;
    #pragma unroll
    for (int c = 0; c < 32; c += 2) {
        unsigned int p = (unsigned int)f2bf(acc[c]) | ((unsigned int)f2bf(acc[c + 1]) << 16);
        *(unsigned int*)(hp + c) = p;
    }
}

// ---------------- fused residual layer ----------------
// block = 512 thr = 8 waves; wave: M=128 out-ch, N=32 positions; grid = 256 (1/CU).
// LDS: 48K conv weights + 16K rs weights + 8*4K out bufs = 96K, all XOR-swizzled rows.
__launch_bounds__(512, 2)
__global__ void layer_kernel(const unsigned short* __restrict__ h_in,
                             unsigned short* __restrict__ h_out,
                             float* __restrict__ skips,
                             const unsigned short* __restrict__ wc,   // [3][128][64] bf16
                             const unsigned short* __restrict__ wr,   // [128][64] bf16
                             const float* __restrict__ gbias,         // [8][128]
                             const float* __restrict__ rsb,           // [128]
                             int dil, int first) {
    __shared__ __align__(16) unsigned char lds[98304];
    unsigned char* ldsA = lds;
    unsigned char* ldsR = lds + 49152;
    unsigned char* ldsO = lds + 65536;
    int tid = threadIdx.x;
    {
        const u32x4* srcA = (const u32x4*)wc;   // 3072 16B chunks
        for (int c = tid; c < 3072; c += 512) {
            int row = c >> 3, wo = c & 7;
            *(u32x4*)(ldsA + row * 128 + ((wo * 16) ^ ((row & 7) << 4))) = srcA[c];
        }
        const u32x4* srcR = (const u32x4*)wr;   // 1024 chunks
        for (int c = tid; c < 1024; c += 512) {
            int row = c >> 3, wo = c & 7;
            *(u32x4*)(ldsR + row * 128 + ((wo * 16) ^ ((row & 7) << 4))) = srcR[c];
        }
    }
    __syncthreads();

    int bid = blockIdx.x;
    int wg = (bid & 7) * 32 + (bid >> 3);       // XCD swizzle: one batch per XCD
    int b = wg >> 5;
    int t0 = ((wg & 31) << 8) + (tid >> 6) * 32;
    int lane = tid & 63;
    int lr = lane & 15;
    int lq = lane >> 4;

    // conv accumulators, init with per-(b,ch) bias (broadcast over positions)
    f32x4 acc[8][2];
    #pragma unroll
    for (int mf = 0; mf < 8; ++mf) {
        f32x4 bias4 = *(const f32x4*)(gbias + b * 128 + mf * 16 + lq * 4);
        acc[mf][0] = bias4;
        acc[mf][1] = bias4;
    }

    const unsigned short* hb = h_in + (size_t)b * Tx * 64;
    #pragma unroll
    for (int tap = 0; tap < 3; ++tap) {
        int toff = (tap - 1) * dil;
        short8 bf[2][2];
        #pragma unroll
        for (int nf = 0; nf < 2; ++nf) {
            int t = t0 + nf * 16 + lr + toff;
            bool v = ((unsigned)t < (unsigned)Tx);
            #pragma unroll
            for (int kc = 0; kc < 2; ++kc) {
                short8 z = {0, 0, 0, 0, 0, 0, 0, 0};
                int hoff = t * 64 + kc * 32 + lq * 8;
                if (v) z = *(const short8*)(hb + hoff);
                bf[nf][kc] = z;
            }
        }
        #pragma unroll
        for (int kc = 0; kc < 2; ++kc) {
            #pragma unroll
            for (int mf = 0; mf < 8; ++mf) {
                int row = tap * 128 + mf * 16 + lr;
                short8 af = *(const short8*)(ldsA + row * 128 + ((kc * 64 + lq * 16) ^ ((lr & 7) << 4)));
                acc[mf][0] = __builtin_amdgcn_mfma_f32_16x16x32_bf16(af, bf[0][kc], acc[mf][0], 0, 0, 0);
                acc[mf][1] = __builtin_amdgcn_mfma_f32_16x16x32_bf16(af, bf[1][kc], acc[mf][1], 0, 0, 0);
            }
        }
    }

    // out = tanh(filt)*sigmoid(gate) = (e^{2f}-1)e^g / ((e^{2f}+1)(1+e^g)); bf16 -> ldsO
    unsigned char* myO = ldsO + (tid >> 6) * 4096;
    #pragma unroll
    for (int mf = 0; mf < 4; ++mf) {
        #pragma unroll
        for (int nf = 0; nf < 2; ++nf) {
            int p = nf * 16 + lr;
            unsigned short ob[4];
            #pragma unroll
            for (int r = 0; r < 4; ++r) {
                float g = acc[mf][nf][r];       // gate: ch 0..63
                float f = acc[mf + 4][nf][r];   // filt: ch 64..127
                f = fminf(f, 15.f);
                g = fminf(g, 30.f);
                float ea = __builtin_amdgcn_exp2f(f * 2.8853900817779268f);
                float eb = __builtin_amdgcn_exp2f(g * 1.4426950408889634f);
                float num = (ea - 1.f) * eb;
                float den = (ea + 1.f) * (1.f + eb);
                ob[r] = f2bf(num * __builtin_amdgcn_rcpf(den));
            }
            u32x2 pk;
            pk[0] = (unsigned int)ob[0] | ((unsigned int)ob[1] << 16);
            pk[1] = (unsigned int)ob[2] | ((unsigned int)ob[3] << 16);
            *(u32x2*)(myO + p * 128 + ((mf * 32 + lq * 8) ^ ((p & 7) << 4))) = pk;
        }
    }
    __syncthreads();

    // rs 1x1 conv: 64 -> 128
    f32x4 racc[8][2];
    #pragma unroll
    for (int mf = 0; mf < 8; ++mf) {
        f32x4 rb4 = *(const f32x4*)(rsb + mf * 16 + lq * 4);
        racc[mf][0] = rb4;
        racc[mf][1] = rb4;
    }
    #pragma unroll
    for (int kc = 0; kc < 2; ++kc) {
        short8 ob2[2];
        #pragma unroll
        for (int nf = 0; nf < 2; ++nf) {
            int p = nf * 16 + lr;
            ob2[nf] = *(const short8*)(myO + p * 128 + ((kc * 64 + lq * 16) ^ ((p & 7) << 4)));
        }
        #pragma unroll
        for (int mf = 0; mf < 8; ++mf) {
            int row = mf * 16 + lr;
            short8 af = *(const short8*)(ldsR + row * 128 + ((kc * 64 + lq * 16) ^ ((lr & 7) << 4)));
            racc[mf][0] = __builtin_amdgcn_mfma_f32_16x16x32_bf16(af, ob2[0], racc[mf][0], 0, 0, 0);
            racc[mf][1] = __builtin_amdgcn_mfma_f32_16x16x32_bf16(af, ob2[1], racc[mf][1], 0, 0, 0);
        }
    }

    // epilogue: h_out = h_in + res/sqrt(2) (bf16), skips += skip (f32)
    const float inv_s2 = 0.70710678118654752f;
    #pragma unroll
    for (int nf = 0; nf < 2; ++nf) {
        int t = t0 + nf * 16 + lr;
        size_t base = ((size_t)b * Tx + t) * 64;
        #pragma unroll
        for (int mf = 0; mf < 4; ++mf) {
            int ch = mf * 16 + lq * 4;
            u32x2 hold = *(const u32x2*)(h_in + base + ch);
            unsigned short* hp = (unsigned short*)&hold;
            unsigned short hnew[4];
            #pragma unroll
            for (int r = 0; r < 4; ++r)
                hnew[r] = f2bf(bf2f(hp[r]) + racc[mf][nf][r] * inv_s2);
            u32x2 hw;
            hw[0] = (unsigned int)hnew[0] | ((unsigned int)hnew[1] << 16);
            hw[1] = (unsigned int)hnew[2] | ((unsigned int)hnew[3] << 16);
            *(u32x2*)(h_out + base + ch) = hw;

            f32x4 sk;
            if (first) { sk[0] = 0.f; sk[1] = 0.f; sk[2] = 0.f; sk[3] = 0.f; }
            else sk = *(const f32x4*)(skips + base + ch);
            sk += racc[mf + 4][nf];
            *(f32x4*)(skips + base + ch) = sk;
        }
    }
}

// ---------------- final: relu(skip_conv(skips/sqrt(30))) -> out_conv, (B,1,80,T) f32 ----------------
__global__ void out_kernel(const float* __restrict__ skips,
                           const float* __restrict__ skw, const float* __restrict__ skb,
                           const float* __restrict__ ow_, const float* __restrict__ ob_,
                           float* __restrict__ y) {
    __shared__ float sw[64][64];
    __shared__ float ow[NM][64];
    int tid = threadIdx.x;
    for (int i = tid; i < 4096; i += 256) sw[i >> 6][i & 63] = skw[i];
    for (int i = tid; i < NM * 64; i += 256) ow[i >> 6][i & 63] = ow_[i];
    __syncthreads();
    int b = blockIdx.y;
    int t = blockIdx.x * 256 + tid;
    const float isc = 0.18257418583505536f;  // 1/sqrt(30)
    const float* sp = skips + ((size_t)b * Tx + t) * 64;
    float s[64];
    #pragma unroll
    for (int c = 0; c < 64; c += 4) {
        f32x4 v = *(const f32x4*)(sp + c);
        s[c] = v[0] * isc; s[c + 1] = v[1] * isc; s[c + 2] = v[2] * isc; s[c + 3] = v[3] * isc;
    }
    float y1[64];
    for (int c2 = 0; c2 < 64; ++c2) {
        float a = skb[c2];
        #pragma unroll
        for (int c = 0; c < 64; ++c) a = fmaf(s[c], sw[c2][c], a);
        y1[c2] = fmaxf(a, 0.f);
    }
    float* yp = y + ((size_t)b * NM) * Tx + t;
    for (int m = 0; m < NM; ++m) {
        float a = ob_[m];
        #pragma unroll
        for (int c = 0; c < 64; ++c) a = fmaf(y1[c], ow[m][c], a);
        yp[(size_t)m * Tx] = a;
    }
}

extern "C" void kernel_launch(void* const* d_in, const int* in_sizes, int n_in,
                              void* d_out, int out_size, void* d_ws, size_t ws_size,
                              hipStream_t stream) {
    const float* x       = (const float*)d_in[0];
    const int*   tin     = (const int*)d_in[1];
    const float* c_emb   = (const float*)d_in[2];
    const float* in_w    = (const float*)d_in[3];
    const float* in_b    = (const float*)d_in[4];
    const float* te_w1   = (const float*)d_in[5];
    const float* te_b1   = (const float*)d_in[6];
    const float* te_w2   = (const float*)d_in[7];
    const float* te_b2   = (const float*)d_in[8];
    const float* dconv_w = (const float*)d_in[9];
    const float* dconv_b = (const float*)d_in[10];
    const float* tproj_w = (const float*)d_in[11];
    const float* tproj_b = (const float*)d_in[12];
    const float* cproj_w = (const float*)d_in[13];
    const float* cproj_b = (const float*)d_in[14];
    const float* rs_w    = (const float*)d_in[15];
    const float* rs_b    = (const float*)d_in[16];
    const float* skip_w  = (const float*)d_in[17];
    const float* skip_b  = (const float*)d_in[18];
    const float* out_w   = (const float*)d_in[19];
    const float* out_b   = (const float*)d_in[20];

    char* ws = (char*)d_ws;
    float* te_buf      = (float*)(ws + 0);              // 8*128*4 = 4KB
    float* gbias       = (float*)(ws + 4096);           // 30*8*128*4 = 120KB
    unsigned short* wc = (unsigned short*)(ws + 131072);   // 30*3*128*64*2 = 1.40625MB
    unsigned short* wr = (unsigned short*)(ws + 1605632);  // 30*128*64*2
    unsigned short* h0 = (unsigned short*)(ws + 2097152);  // 8*8192*64*2 = 8MB
    unsigned short* h1 = (unsigned short*)(ws + 10485760);
    float* skips       = (float*)(ws + 18874368);          // 8*8192*64*4 = 16MB (end 34MB)

    te_kernel<<<1, 512, 0, stream>>>(tin, te_w1, te_b1, te_w2, te_b2, te_buf);
    gbias_kernel<<<240, 128, 0, stream>>>(te_buf, c_emb, tproj_w, tproj_b,
                                          cproj_w, cproj_b, dconv_b, gbias);
    prep_kernel<<<3840, 256, 0, stream>>>(dconv_w, rs_w, wc, wr);
    in_conv_kernel<<<dim3(64, 8), 256, 0, stream>>>(x, in_w, in_b, h0);

    unsigned short* hin = h0;
    unsigned short* hout = h1;
    for (int i = 0; i < NL; ++i) {
        int dil = 1 << (i % 10);
        layer_kernel<<<256, 512, 0, stream>>>(hin, hout, skips,
                                              wc + (size_t)i * 24576,
                                              wr + (size_t)i * 8192,
                                              gbias + (size_t)i * 1024,
                                              rs_b + (size_t)i * 128,
                                              dil, i == 0 ? 1 : 0);
        unsigned short* tmp = hin; hin = hout; hout = tmp;
    }
    out_kernel<<<dim3(32, 8), 256, 0, stream>>>(skips, skip_w, skip_b, out_w, out_b,
                                                (float*)d_out);
}